// Round 4
// baseline (193.268 us; speedup 1.0000x reference)
//
#include <hip/hip_runtime.h>

// DSQG attention, J=12 causal offsets, f32.
// One 16-lane group per position; lane holds 4 channels (float4).
// R4: DPP reductions (ctrl as template arg — must be an immediate),
// distributed phase rotation across lanes g=0..11, mask-free fast path.

namespace {

constexpr int J   = 12;
constexpr int B_  = 2;
constexpr int H_  = 16;
constexpr int N_  = 4096;
constexpr int OFFS[J] = {1, 2, 4, 8, 16, 64, 96, 192, 384, 512, 768, 1024};

template <int CTRL>
__device__ __forceinline__ float dpp_add(float x) {
    int t = __builtin_amdgcn_update_dpp(0, __float_as_int(x), CTRL, 0xf, 0xf, true);
    return x + __int_as_float(t);
}

// sum across an aligned 16-lane group; every lane gets the total
__device__ __forceinline__ float row16_reduce(float x) {
    x = dpp_add<0xB1>(x);   // quad_perm [1,0,3,2]  (xor 1)
    x = dpp_add<0x4E>(x);   // quad_perm [2,3,0,1]  (xor 2)
    x = dpp_add<0x141>(x);  // row_half_mirror      (combines quads)
    x = dpp_add<0x140>(x);  // row_mirror           (combines halves)
    return x;
}

template <bool MASKED>
__device__ __forceinline__ void body(
    int n, int grp, int h, size_t bhN,
    const float4* __restrict__ q4, const float4* __restrict__ k4,
    const float4* __restrict__ v4, float4* __restrict__ o4,
    const float* __restrict__ pb, const float4* __restrict__ se4,
    const float2* __restrict__ pbase2, const float2* __restrict__ pgain2,
    const float2* __restrict__ y2, const float2* __restrict__ z2)
{
    const float4 qr = q4[(size_t)n * 16 + grp];

    int m[J];
#pragma unroll
    for (int i = 0; i < J; ++i) {
        if (MASKED) m[i] = (n >= OFFS[i]) ? (n - OFFS[i]) : 0;
        else        m[i] = n - OFFS[i];
    }

    // ---- per-lane role for the channel-0..3 (rotation) work ----------------
    // g in [0,8): rotated offset i=g+4; g in [8,12): plain offset j=g-8.
    const int g = grp;
    int dg = 16;
    dg = (g == 1) ? 64   : dg;
    dg = (g == 2) ? 96   : dg;
    dg = (g == 3) ? 192  : dg;
    dg = (g == 4) ? 384  : dg;
    dg = (g == 5) ? 512  : dg;
    dg = (g == 6) ? 768  : dg;
    dg = (g == 7) ? 1024 : dg;
    dg = (g == 8) ? 1    : dg;
    dg = (g == 9) ? 2    : dg;
    dg = (g == 10) ? 4   : dg;
    dg = (g == 11) ? 8   : dg;
    int mg = n - dg;
    mg = (mg < 0) ? 0 : mg;

    // early small loads (independent of k/v row loads)
    const float2 yp    = y2[bhN + n];
    const float4 vhead = v4[(size_t)mg * 16];     // channels 0..3 of row mg
    const float2 zg    = z2[bhN + mg];
    const int    pi8   = g & 7;
    const float2 pbse  = pbase2[pi8 * H_ + h];
    const float2 pgn   = pgain2[pi8 * H_ + h];

    // ---- bulk row loads -----------------------------------------------------
    float4 kr[J];
#pragma unroll
    for (int i = 0; i < J; ++i) kr[i] = k4[(size_t)m[i] * 16 + grp];
    float4 vr[J];
#pragma unroll
    for (int i = 0; i < J; ++i) vr[i] = v4[(size_t)m[i] * 16 + grp];

    // ---- scores: p_i = q . (k_i + se_i), reduced across the 16-lane group ---
    float p[J];
#pragma unroll
    for (int i = 0; i < J; ++i) {
        const float4 seg = se4[i * 16 + grp];
        float t;
        t = qr.x * (kr[i].x + seg.x);
        t = fmaf(qr.y, kr[i].y + seg.y, t);
        t = fmaf(qr.z, kr[i].z + seg.z, t);
        t = fmaf(qr.w, kr[i].w + seg.w, t);
        p[i] = row16_reduce(t);
    }

    float e[J];
    float sum = 0.f;
#pragma unroll
    for (int i = 0; i < J; ++i) {
        const float si = fmaf(p[i], 0.125f, pb[i * H_ + h]);
        const bool ok = MASKED ? (n >= OFFS[i]) : true;
        e[i] = ok ? __expf(si) : 0.f;   // max-free: |si| ~ O(6), f32-safe
        sum += e[i];
    }

    // ---- distributed rotation: lane g computes its offset's ch0..3 term -----
    float esel = e[4];
    esel = (g == 1) ? e[5]  : esel;
    esel = (g == 2) ? e[6]  : esel;
    esel = (g == 3) ? e[7]  : esel;
    esel = (g == 4) ? e[8]  : esel;
    esel = (g == 5) ? e[9]  : esel;
    esel = (g == 6) ? e[10] : esel;
    esel = (g == 7) ? e[11] : esel;
    esel = (g == 8) ? e[0]  : esel;
    esel = (g == 9) ? e[1]  : esel;
    esel = (g == 10) ? e[2] : esel;
    esel = (g == 11) ? e[3] : esel;

    const float th0 = fmaf(pgn.x, yp.x * zg.x, pbse.x);
    const float th1 = fmaf(pgn.y, yp.y * zg.y, pbse.y);
    const float c0 = __cosf(th0), s0 = __sinf(th0);
    const float c1 = __cosf(th1), s1 = __sinf(th1);

    const bool isrot = (g < 8);
    float cx = isrot ? (c0 * vhead.x - s0 * vhead.y) : vhead.x;
    float cy = isrot ? (s0 * vhead.x + c0 * vhead.y) : vhead.y;
    float cz = isrot ? (c1 * vhead.z - s1 * vhead.w) : vhead.z;
    float cw = isrot ? (s1 * vhead.z + c1 * vhead.w) : vhead.w;
    const float wgt = (g < 12) ? esel : 0.f;
    cx *= wgt; cy *= wgt; cz *= wgt; cw *= wgt;
    cx = row16_reduce(cx);
    cy = row16_reduce(cy);
    cz = row16_reduce(cz);
    cw = row16_reduce(cw);

    // ---- standard weighted sum for channels 4..63 ---------------------------
    float4 acc = make_float4(0.f, 0.f, 0.f, 0.f);
#pragma unroll
    for (int i = 0; i < J; ++i) {
        acc.x = fmaf(e[i], vr[i].x, acc.x);
        acc.y = fmaf(e[i], vr[i].y, acc.y);
        acc.z = fmaf(e[i], vr[i].z, acc.z);
        acc.w = fmaf(e[i], vr[i].w, acc.w);
    }
    if (g == 0) { acc.x = cx; acc.y = cy; acc.z = cz; acc.w = cw; }

    float4 res;
    if (!MASKED || n >= 1) {
        const float inv = 1.0f / sum;
        res = make_float4(acc.x * inv, acc.y * inv, acc.z * inv, acc.w * inv);
    } else {
        res = make_float4(0.f, 0.f, 0.f, 0.f);
    }
    o4[(size_t)n * 16 + grp] = res;
}

__global__ __launch_bounds__(256, 4) void dsqg_kernel(
    const float* __restrict__ q, const float* __restrict__ k,
    const float* __restrict__ v, const float* __restrict__ pb,
    const float* __restrict__ se, const float* __restrict__ phase_base,
    const float* __restrict__ phase_gain, const float* __restrict__ y_pre,
    const float* __restrict__ z_pre, float* __restrict__ out)
{
    // XCD-locality swizzle: contiguous work range per XCD
    const int raw = blockIdx.x;
    const int per = gridDim.x >> 3;
    const int wid = (raw & 7) * per + (raw >> 3);

    const int bh    = wid >> 8;
    const int chunk = wid & 255;
    const int h     = bh & (H_ - 1);

    const int lane = threadIdx.x & 63;
    const int wave = threadIdx.x >> 6;
    const int grp  = lane & 15;
    const int n    = chunk * 16 + wave * 4 + (lane >> 4);

    const size_t base4 = (size_t)bh * N_ * 16;    // float4 units
    const float4* q4 = (const float4*)q + base4;
    const float4* k4 = (const float4*)k + base4;
    const float4* v4 = (const float4*)v + base4;
    float4*       o4 = (float4*)out + base4;
    const size_t bhN = (size_t)bh * N_;

    if (chunk >= 64) {   // n >= 1024: every offset valid, no masking needed
        body<false>(n, grp, h, bhN, q4, k4, v4, o4, pb, (const float4*)se,
                    (const float2*)phase_base, (const float2*)phase_gain,
                    (const float2*)y_pre, (const float2*)z_pre);
    } else {
        body<true>(n, grp, h, bhN, q4, k4, v4, o4, pb, (const float4*)se,
                   (const float2*)phase_base, (const float2*)phase_gain,
                   (const float2*)y_pre, (const float2*)z_pre);
    }
}

} // namespace

extern "C" void kernel_launch(void* const* d_in, const int* in_sizes, int n_in,
                              void* d_out, int out_size, void* d_ws, size_t ws_size,
                              hipStream_t stream) {
    const float* q          = (const float*)d_in[0];
    const float* k          = (const float*)d_in[1];
    const float* v          = (const float*)d_in[2];
    const float* pb         = (const float*)d_in[3];
    const float* se         = (const float*)d_in[4];
    const float* phase_base = (const float*)d_in[5];
    const float* phase_gain = (const float*)d_in[6];
    const float* y_pre      = (const float*)d_in[7];
    const float* z_pre      = (const float*)d_in[8];
    float* out              = (float*)d_out;

    const int positions = B_ * H_ * N_;          // 131072
    const int blocks    = positions / 16;        // 16 positions per 256-thread block
    dsqg_kernel<<<blocks, 256, 0, stream>>>(q, k, v, pb, se, phase_base,
                                            phase_gain, y_pre, z_pre, out);
}